// Round 9
// baseline (534.036 us; speedup 1.0000x reference)
//
#include <hip/hip_runtime.h>
#include <hip/hip_bf16.h>

// EnhancedTelomeraseGNN on MI355X — round 9.
// f32 in/out. GEMMs on MFMA (16x16x32 bf16, split-bf16 hi/lo). a_e=ea*p+q.
// Round-9: (1) k_gat pass-B 4-edge-parallel channel-split gather (grp=edge,
// cl=16-ch slice, shfl src broadcast) — serial chain deg->deg/4. (2) k_agg
// same restructure. (3) k_scan 2-barrier range-scan. (4) scatter atomicSub
// (drops a memset). (5) k_pq folded into k_prep.
//
// Workspace (~76 MB, overlaid): pq | cnt | off | csr_src | csr_ea | as | ad |
// hmat bf16[N,256] | nodeB f32[N,64] | agg f32[N,64] | B-planes | R(19.2MB):
// A1 planes -> A2 planes -> sage-out f32 | gbuf.

#define NN 50000
#define NE 400000
#define FIN 32
#define NBATCH 64

typedef __hip_bfloat16 bf16;
typedef short bf16x8 __attribute__((ext_vector_type(8)));
typedef float f32x4 __attribute__((ext_vector_type(4)));

__device__ __forceinline__ float b2f(bf16 v) { return __bfloat162float(v); }
__device__ __forceinline__ float lrelu(float x) { return x > 0.f ? x : 0.2f * x; }
__device__ __forceinline__ float eluf(float x) { return x > 0.f ? x : (expf(x) - 1.f); }

__device__ __forceinline__ float4 f4fma(float s, float4 w, float4 c) {
  c.x = fmaf(s, w.x, c.x); c.y = fmaf(s, w.y, c.y);
  c.z = fmaf(s, w.z, c.z); c.w = fmaf(s, w.w, c.w);
  return c;
}

__device__ __forceinline__ float4 upk4(unsigned int lo, unsigned int hi) {
  float4 f;
  f.x = __uint_as_float(lo << 16);
  f.y = __uint_as_float(lo & 0xffff0000u);
  f.z = __uint_as_float(hi << 16);
  f.w = __uint_as_float(hi & 0xffff0000u);
  return f;
}

__device__ __forceinline__ unsigned short bfbits(float f) {
  bf16 b = __float2bfloat16(f);
  unsigned short u;
  __builtin_memcpy(&u, &b, 2);
  return u;
}
__device__ __forceinline__ float hi_f(unsigned short u) {
  return __uint_as_float((unsigned int)u << 16);
}

// ------------------------------------------------------- prep: splitW + pq
__global__ __launch_bounds__(256) void k_prep(
    const float* __restrict__ W1, const float* __restrict__ W2,
    const float* __restrict__ We1, const float* __restrict__ atte1,
    const float* __restrict__ We2, const float* __restrict__ atte2,
    const float* __restrict__ edgeW, const float* __restrict__ edgeB,
    unsigned short* __restrict__ B1h, unsigned short* __restrict__ B1l,
    unsigned short* __restrict__ B2h, unsigned short* __restrict__ B2l,
    float* __restrict__ pq) {
  if (blockIdx.x == 96) {
    int t = threadIdx.x, h = t >> 6, c = t & 63;
    float sW1 = 0.f, sB1 = 0.f, sW2 = 0.f, sB2 = 0.f;
    for (int j = 0; j < 64; ++j) {
      float w = edgeW[j], b = edgeB[j];
      float we1 = We1[j * 256 + h * 64 + c];
      float we2 = We2[j * 256 + h * 64 + c];
      sW1 += w * we1; sB1 += b * we1;
      sW2 += w * we2; sB2 += b * we2;
    }
    float a1 = atte1[h * 64 + c], a2 = atte2[h * 64 + c];
    float p1 = sW1 * a1, q1 = sB1 * a1, p2 = sW2 * a2, q2 = sB2 * a2;
    for (int o = 32; o; o >>= 1) {
      p1 += __shfl_xor(p1, o); q1 += __shfl_xor(q1, o);
      p2 += __shfl_xor(p2, o); q2 += __shfl_xor(q2, o);
    }
    if (c == 0) { pq[h] = p1; pq[4 + h] = q1; pq[8 + h] = p2; pq[12 + h] = q2; }
    return;
  }
  int t = blockIdx.x * 256 + threadIdx.x;
  if (t < 256 * 96) {
    int n = t / 96, k = t - n * 96;
    float v = W1[k * 256 + n];
    unsigned short h = bfbits(v);
    B1h[t] = h; B1l[t] = bfbits(v - hi_f(h));
  }
  if (t < 256 * 64) {
    int n = t >> 6, k = t & 63;
    float v = W2[k * 256 + n];
    unsigned short h = bfbits(v);
    B2h[t] = h; B2l[t] = bfbits(v - hi_f(h));
  }
}

// ---------------------------------------------------------------- CSR build
__global__ void k_hist(const int* __restrict__ dst, int* __restrict__ cnt) {
  int e = blockIdx.x * 256 + threadIdx.x;
  if (e < NE) atomicAdd(&cnt[dst[e]], 1);
}

// 2-barrier range scan: thread t owns cnt[t*PER .. t*PER+PER).
__global__ __launch_bounds__(1024) void k_scan(const int* __restrict__ cnt,
                                               int* __restrict__ off) {
  __shared__ int wsum[16];
  int t = threadIdx.x, lane = t & 63, w = t >> 6;
  const int PER = (NN + 1023) / 1024;
  int base = t * PER;
  int n = NN - base;
  if (n < 0) n = 0;
  if (n > PER) n = PER;
  int s = 0;
  for (int i = 0; i < n; ++i) s += cnt[base + i];
  int ps = s;
  for (int o = 1; o < 64; o <<= 1) { int u = __shfl_up(ps, o); if (lane >= o) ps += u; }
  if (lane == 63) wsum[w] = ps;
  __syncthreads();
  if (t < 16) {
    int ws = wsum[t];
    for (int o = 1; o < 16; o <<= 1) { int u = __shfl_up(ws, o); if (t >= o) ws += u; }
    wsum[t] = ws;
  }
  __syncthreads();
  int run = (ps - s) + (w ? wsum[w - 1] : 0);
  if (t == 0) off[0] = 0;
  for (int i = 0; i < n; ++i) { run += cnt[base + i]; off[base + i + 1] = run; }
}

// scatter via atomicSub on live cnt (slot = off[d] + remaining - 1)
__global__ void k_scatter(const int* __restrict__ src, const int* __restrict__ dst,
                          const float* __restrict__ ea, const int* __restrict__ off,
                          int* __restrict__ cnt, int* __restrict__ csr_src,
                          float* __restrict__ csr_ea) {
  int e = blockIdx.x * 256 + threadIdx.x;
  if (e >= NE) return;
  int d = dst[e];
  int r = atomicSub(&cnt[d], 1);
  int slot = off[d] + r - 1;
  csr_src[slot] = src[e];
  csr_ea[slot] = ea[e];
}

// ---------------------------------------------------------------- split prep
__global__ __launch_bounds__(256) void k_splitA(
    const float* __restrict__ x, const int* __restrict__ ntype,
    const float* __restrict__ emb, unsigned short* __restrict__ Ah,
    unsigned short* __restrict__ Al) {
  const int total = NN * 96;
  for (int i = blockIdx.x * 256 + threadIdx.x; i < total; i += gridDim.x * 256) {
    int n = i / 96, k = i - n * 96;
    float v = (k < FIN) ? x[n * FIN + k] : emb[ntype[n] * 64 + (k - FIN)];
    unsigned short h = bfbits(v);
    Ah[i] = h;
    Al[i] = bfbits(v - hi_f(h));
  }
}

// ---------------------------------------------------------------- MFMA GEMM
template <int K>
__global__ __launch_bounds__(256) void k_mm_mfma(
    const unsigned short* __restrict__ Ah, const unsigned short* __restrict__ Al,
    const unsigned short* __restrict__ Bh, const unsigned short* __restrict__ Bl,
    const float* __restrict__ atts, const float* __restrict__ attd,
    bf16* __restrict__ hmat, float* __restrict__ as_, float* __restrict__ ad_) {
  int m0 = blockIdx.x * 64;
  int w = threadIdx.x >> 6;     // wave = head
  int lane = threadIdx.x & 63;
  int lr = lane & 15;
  int lc = lane >> 4;
  float attsv[4], attdv[4];
  #pragma unroll
  for (int nt = 0; nt < 4; ++nt) {
    attsv[nt] = atts[w * 64 + nt * 16 + lr];
    attdv[nt] = attd[w * 64 + nt * 16 + lr];
  }
  f32x4 acc[4][4] = {};
  #pragma unroll
  for (int ks = 0; ks < K; ks += 32) {
    int koff = ks + lc * 8;
    bf16x8 ah[4], al[4], bh[4], bl[4];
    #pragma unroll
    for (int mt = 0; mt < 4; ++mt) {
      int m = m0 + mt * 16 + lr;
      if (m > NN - 1) m = NN - 1;
      ah[mt] = *reinterpret_cast<const bf16x8*>(&Ah[(size_t)m * K + koff]);
      al[mt] = *reinterpret_cast<const bf16x8*>(&Al[(size_t)m * K + koff]);
    }
    #pragma unroll
    for (int nt = 0; nt < 4; ++nt) {
      int n = w * 64 + nt * 16 + lr;
      bh[nt] = *reinterpret_cast<const bf16x8*>(&Bh[(size_t)n * K + koff]);
      bl[nt] = *reinterpret_cast<const bf16x8*>(&Bl[(size_t)n * K + koff]);
    }
    #pragma unroll
    for (int mt = 0; mt < 4; ++mt) {
      #pragma unroll
      for (int nt = 0; nt < 4; ++nt) {
        acc[mt][nt] = __builtin_amdgcn_mfma_f32_16x16x32_bf16(ah[mt], bh[nt], acc[mt][nt], 0, 0, 0);
        acc[mt][nt] = __builtin_amdgcn_mfma_f32_16x16x32_bf16(al[mt], bh[nt], acc[mt][nt], 0, 0, 0);
        acc[mt][nt] = __builtin_amdgcn_mfma_f32_16x16x32_bf16(ah[mt], bl[nt], acc[mt][nt], 0, 0, 0);
      }
    }
  }
  #pragma unroll
  for (int mt = 0; mt < 4; ++mt) {
    #pragma unroll
    for (int reg = 0; reg < 4; ++reg) {
      int row = m0 + mt * 16 + lc * 4 + reg;
      float sS = 0.f, sD = 0.f;
      #pragma unroll
      for (int nt = 0; nt < 4; ++nt) {
        float v = acc[mt][nt][reg];
        sS += v * attsv[nt];
        sD += v * attdv[nt];
      }
      for (int o = 1; o < 16; o <<= 1) {
        sS += __shfl_xor(sS, o);
        sD += __shfl_xor(sD, o);
      }
      if (row < NN) {
        #pragma unroll
        for (int nt = 0; nt < 4; ++nt)
          hmat[(size_t)row * 256 + w * 64 + nt * 16 + lr] =
              __float2bfloat16(acc[mt][nt][reg]);
        if (lr == 0) { as_[row * 4 + w] = sS; ad_[row * 4 + w] = sD; }
      }
    }
  }
}

// ---------------------------------------------------------------- GAT
// Wave per dst node. Fast path (deg<=64): pass A lane=edge (logits+softmax,
// weights -> per-wave LDS, src kept in register). Pass B: 4 edges in flight
// (grp=lane>>4), lane covers 16 flat channels (cl=lane&15); shfl src
// broadcast; reduce via shfl_xor{16,32} (grps) + {4,8} (heads).
__global__ __launch_bounds__(256) void k_gat(
    const int* __restrict__ off, const int* __restrict__ csr_src,
    const float* __restrict__ csr_ea, const float* __restrict__ as_,
    const float* __restrict__ ad_, const float* __restrict__ pq, int pqo,
    const bf16* __restrict__ hmat, const float* __restrict__ bias,
    float* __restrict__ outf, unsigned short* __restrict__ oph,
    unsigned short* __restrict__ opl) {
  __shared__ float wlds[4][256];
  int wv = threadIdx.x >> 6;
  int wid = (blockIdx.x << 2) + wv;
  int lane = threadIdx.x & 63;
  if (wid >= NN) return;
  int beg = off[wid], end = off[wid + 1];
  int deg = end - beg;
  float4 D = reinterpret_cast<const float4*>(ad_)[wid];
  float p0 = pq[pqo + 0], p1 = pq[pqo + 1], p2 = pq[pqo + 2], p3 = pq[pqo + 3];
  float q0 = pq[pqo + 4], q1 = pq[pqo + 5], q2 = pq[pqo + 6], q3 = pq[pqo + 7];

  if (deg <= 64) {
    bool valid = lane < deg;
    int se = 0;
    float lx = -INFINITY, ly = -INFINITY, lz = -INFINITY, lw = -INFINITY;
    if (valid) {
      se = csr_src[beg + lane];
      float ea = csr_ea[beg + lane];
      float4 A = reinterpret_cast<const float4*>(as_)[se];
      lx = lrelu(A.x + D.x + ea * p0 + q0);
      ly = lrelu(A.y + D.y + ea * p1 + q1);
      lz = lrelu(A.z + D.z + ea * p2 + q2);
      lw = lrelu(A.w + D.w + ea * p3 + q3);
    }
    float m0 = lx, m1 = ly, m2 = lz, m3 = lw;
    for (int o = 32; o; o >>= 1) {
      m0 = fmaxf(m0, __shfl_xor(m0, o));
      m1 = fmaxf(m1, __shfl_xor(m1, o));
      m2 = fmaxf(m2, __shfl_xor(m2, o));
      m3 = fmaxf(m3, __shfl_xor(m3, o));
    }
    float w0 = valid ? __expf(lx - m0) : 0.f;
    float w1 = valid ? __expf(ly - m1) : 0.f;
    float w2 = valid ? __expf(lz - m2) : 0.f;
    float w3 = valid ? __expf(lw - m3) : 0.f;
    float s0 = w0, s1 = w1, s2 = w2, s3 = w3;
    for (int o = 32; o; o >>= 1) {
      s0 += __shfl_xor(s0, o); s1 += __shfl_xor(s1, o);
      s2 += __shfl_xor(s2, o); s3 += __shfl_xor(s3, o);
    }
    float4 wv4;
    wv4.x = w0 / (s0 + 1e-16f);
    wv4.y = w1 / (s1 + 1e-16f);
    wv4.z = w2 / (s2 + 1e-16f);
    wv4.w = w3 / (s3 + 1e-16f);
    reinterpret_cast<float4*>(&wlds[wv][0])[lane] = wv4;
    // pass B: 4 edges in flight, 16-channel slices
    int grp = lane >> 4, cl = lane & 15;
    int hsl = cl >> 2;  // head of this slice
    const float* wp = &wlds[wv][0];
    float4 a0 = {0.f, 0.f, 0.f, 0.f}, a1 = a0, a2 = a0, a3 = a0;
    for (int jb = 0; jb < deg; jb += 4) {
      int j = jb + grp;
      if (j < deg) {
        int s = __shfl(se, j);
        float w = wp[4 * j + hsl];
        const bf16* hp = &hmat[(size_t)s * 256 + cl * 16];
        uint4 u0 = *reinterpret_cast<const uint4*>(hp);
        uint4 u1 = *reinterpret_cast<const uint4*>(hp + 8);
        a0 = f4fma(w, upk4(u0.x, u0.y), a0);
        a1 = f4fma(w, upk4(u0.z, u0.w), a1);
        a2 = f4fma(w, upk4(u1.x, u1.y), a2);
        a3 = f4fma(w, upk4(u1.z, u1.w), a3);
      }
    }
    // full reduce over xor{4,8,16,32}: sums grps and heads (out-ch = f(cl&3))
    #pragma unroll
    for (int o = 4; o <= 32; o <<= 1) {
      a0.x += __shfl_xor(a0.x, o); a0.y += __shfl_xor(a0.y, o);
      a0.z += __shfl_xor(a0.z, o); a0.w += __shfl_xor(a0.w, o);
      a1.x += __shfl_xor(a1.x, o); a1.y += __shfl_xor(a1.y, o);
      a1.z += __shfl_xor(a1.z, o); a1.w += __shfl_xor(a1.w, o);
      a2.x += __shfl_xor(a2.x, o); a2.y += __shfl_xor(a2.y, o);
      a2.z += __shfl_xor(a2.z, o); a2.w += __shfl_xor(a2.w, o);
      a3.x += __shfl_xor(a3.x, o); a3.y += __shfl_xor(a3.y, o);
      a3.z += __shfl_xor(a3.z, o); a3.w += __shfl_xor(a3.w, o);
    }
    if (lane < 4) {  // lane = out-channel block (16 ch each)
      float4 rr0 = a0, rr1 = a1, rr2 = a2, rr3 = a3;
      float4 b0 = reinterpret_cast<const float4*>(bias)[lane * 4 + 0];
      float4 b1v = reinterpret_cast<const float4*>(bias)[lane * 4 + 1];
      float4 b2v = reinterpret_cast<const float4*>(bias)[lane * 4 + 2];
      float4 b3v = reinterpret_cast<const float4*>(bias)[lane * 4 + 3];
      rr0.x = eluf(0.25f * rr0.x + b0.x); rr0.y = eluf(0.25f * rr0.y + b0.y);
      rr0.z = eluf(0.25f * rr0.z + b0.z); rr0.w = eluf(0.25f * rr0.w + b0.w);
      rr1.x = eluf(0.25f * rr1.x + b1v.x); rr1.y = eluf(0.25f * rr1.y + b1v.y);
      rr1.z = eluf(0.25f * rr1.z + b1v.z); rr1.w = eluf(0.25f * rr1.w + b1v.w);
      rr2.x = eluf(0.25f * rr2.x + b2v.x); rr2.y = eluf(0.25f * rr2.y + b2v.y);
      rr2.z = eluf(0.25f * rr2.z + b2v.z); rr2.w = eluf(0.25f * rr2.w + b2v.w);
      rr3.x = eluf(0.25f * rr3.x + b3v.x); rr3.y = eluf(0.25f * rr3.y + b3v.y);
      rr3.z = eluf(0.25f * rr3.z + b3v.z); rr3.w = eluf(0.25f * rr3.w + b3v.w);
      if (outf) {
        float4* o = reinterpret_cast<float4*>(&outf[(size_t)wid * 64 + lane * 16]);
        o[0] = rr0; o[1] = rr1; o[2] = rr2; o[3] = rr3;
      }
      if (oph) {
        float4 rr[4] = {rr0, rr1, rr2, rr3};
        #pragma unroll
        for (int i = 0; i < 4; ++i) {
          ushort4 h4, l4;
          h4.x = bfbits(rr[i].x); l4.x = bfbits(rr[i].x - hi_f(h4.x));
          h4.y = bfbits(rr[i].y); l4.y = bfbits(rr[i].y - hi_f(h4.y));
          h4.z = bfbits(rr[i].z); l4.z = bfbits(rr[i].z - hi_f(h4.z));
          h4.w = bfbits(rr[i].w); l4.w = bfbits(rr[i].w - hi_f(h4.w));
          *reinterpret_cast<ushort4*>(&oph[(size_t)wid * 64 + lane * 16 + i * 4]) = h4;
          *reinterpret_cast<ushort4*>(&opl[(size_t)wid * 64 + lane * 16 + i * 4]) = l4;
        }
      }
    }
  } else {
    // slow fallback for deg > 64 — original serial structure + old epilogue
    int hsel = lane >> 4;
    float m0 = -INFINITY, m1 = -INFINITY, m2 = -INFINITY, m3 = -INFINITY;
    float s0 = 0.f, s1 = 0.f, s2 = 0.f, s3 = 0.f;
    for (int e = beg + lane; e < end; e += 64) {
      int s = csr_src[e];
      float ea = csr_ea[e];
      float4 A = reinterpret_cast<const float4*>(as_)[s];
      float lx = lrelu(A.x + D.x + ea * p0 + q0);
      float ly = lrelu(A.y + D.y + ea * p1 + q1);
      float lz = lrelu(A.z + D.z + ea * p2 + q2);
      float lw = lrelu(A.w + D.w + ea * p3 + q3);
      float nm;
      nm = fmaxf(m0, lx); s0 = s0 * __expf(m0 - nm) + __expf(lx - nm); m0 = nm;
      nm = fmaxf(m1, ly); s1 = s1 * __expf(m1 - nm) + __expf(ly - nm); m1 = nm;
      nm = fmaxf(m2, lz); s2 = s2 * __expf(m2 - nm) + __expf(lz - nm); m2 = nm;
      nm = fmaxf(m3, lw); s3 = s3 * __expf(m3 - nm) + __expf(lw - nm); m3 = nm;
    }
    for (int o = 32; o; o >>= 1) {
      float om, os, nm;
      om = __shfl_xor(m0, o); os = __shfl_xor(s0, o); nm = fmaxf(m0, om);
      s0 = s0 * __expf(fmaxf(m0 - nm, -80.f)) + os * __expf(fmaxf(om - nm, -80.f)); m0 = nm;
      om = __shfl_xor(m1, o); os = __shfl_xor(s1, o); nm = fmaxf(m1, om);
      s1 = s1 * __expf(fmaxf(m1 - nm, -80.f)) + os * __expf(fmaxf(om - nm, -80.f)); m1 = nm;
      om = __shfl_xor(m2, o); os = __shfl_xor(s2, o); nm = fmaxf(m2, om);
      s2 = s2 * __expf(fmaxf(m2 - nm, -80.f)) + os * __expf(fmaxf(om - nm, -80.f)); m2 = nm;
      om = __shfl_xor(m3, o); os = __shfl_xor(s3, o); nm = fmaxf(m3, om);
      s3 = s3 * __expf(fmaxf(m3 - nm, -80.f)) + os * __expf(fmaxf(om - nm, -80.f)); m3 = nm;
    }
    float i0 = 1.f / (s0 + 1e-16f), i1 = 1.f / (s1 + 1e-16f);
    float i2 = 1.f / (s2 + 1e-16f), i3 = 1.f / (s3 + 1e-16f);
    float Dh = hsel == 0 ? D.x : hsel == 1 ? D.y : hsel == 2 ? D.z : D.w;
    float ph = hsel == 0 ? p0 : hsel == 1 ? p1 : hsel == 2 ? p2 : p3;
    float qh = hsel == 0 ? q0 : hsel == 1 ? q1 : hsel == 2 ? q2 : q3;
    float mh = hsel == 0 ? m0 : hsel == 1 ? m1 : hsel == 2 ? m2 : m3;
    float ih = hsel == 0 ? i0 : hsel == 1 ? i1 : hsel == 2 ? i2 : i3;
    float4 acc = {0.f, 0.f, 0.f, 0.f};
    for (int j = beg; j < end; ++j) {
      int s = csr_src[j];
      float ea = csr_ea[j];
      float4 A = reinterpret_cast<const float4*>(as_)[s];
      float Ah = hsel == 0 ? A.x : hsel == 1 ? A.y : hsel == 2 ? A.z : A.w;
      float l = lrelu(Ah + Dh + ea * ph + qh);
      float w = __expf(l - mh) * ih;
      uint2 u = *reinterpret_cast<const uint2*>(&hmat[(size_t)s * 256 + 4 * lane]);
      acc = f4fma(w, upk4(u.x, u.y), acc);
    }
    acc.x += __shfl_xor(acc.x, 16); acc.y += __shfl_xor(acc.y, 16);
    acc.z += __shfl_xor(acc.z, 16); acc.w += __shfl_xor(acc.w, 16);
    acc.x += __shfl_xor(acc.x, 32); acc.y += __shfl_xor(acc.y, 32);
    acc.z += __shfl_xor(acc.z, 32); acc.w += __shfl_xor(acc.w, 32);
    if (lane < 16) {
      float4 bv = reinterpret_cast<const float4*>(bias)[lane];
      float4 r;
      r.x = eluf(0.25f * acc.x + bv.x);
      r.y = eluf(0.25f * acc.y + bv.y);
      r.z = eluf(0.25f * acc.z + bv.z);
      r.w = eluf(0.25f * acc.w + bv.w);
      if (outf) reinterpret_cast<float4*>(&outf[(size_t)wid * 64])[lane] = r;
      if (oph) {
        ushort4 h4, l4;
        h4.x = bfbits(r.x); l4.x = bfbits(r.x - hi_f(h4.x));
        h4.y = bfbits(r.y); l4.y = bfbits(r.y - hi_f(h4.y));
        h4.z = bfbits(r.z); l4.z = bfbits(r.z - hi_f(h4.z));
        h4.w = bfbits(r.w); l4.w = bfbits(r.w - hi_f(h4.w));
        *reinterpret_cast<ushort4*>(&oph[(size_t)wid * 64 + lane * 4]) = h4;
        *reinterpret_cast<ushort4*>(&opl[(size_t)wid * 64 + lane * 4]) = l4;
      }
    }
  }
}

// ---------------------------------------------------------------- SAGE agg
// Same 4-edge-parallel scheme: grp=edge-in-flight, cl covers 4 f32 channels.
__global__ __launch_bounds__(256) void k_agg(
    const int* __restrict__ off, const int* __restrict__ csr_src,
    const float* __restrict__ h3, float* __restrict__ agg) {
  int wid = (blockIdx.x << 2) + (threadIdx.x >> 6);
  int lane = threadIdx.x & 63;
  if (wid >= NN) return;
  int beg = off[wid], end = off[wid + 1];
  int deg = end - beg;
  if (deg <= 64) {
    int se = (lane < deg) ? csr_src[beg + lane] : 0;
    int grp = lane >> 4, cl = lane & 15;
    float4 acc = {0.f, 0.f, 0.f, 0.f};
    for (int jb = 0; jb < deg; jb += 4) {
      int j = jb + grp;
      if (j < deg) {
        int s = __shfl(se, j);
        float4 v = *reinterpret_cast<const float4*>(&h3[(size_t)s * 64 + cl * 4]);
        acc.x += v.x; acc.y += v.y; acc.z += v.z; acc.w += v.w;
      }
    }
    #pragma unroll
    for (int o = 16; o <= 32; o <<= 1) {
      acc.x += __shfl_xor(acc.x, o); acc.y += __shfl_xor(acc.y, o);
      acc.z += __shfl_xor(acc.z, o); acc.w += __shfl_xor(acc.w, o);
    }
    if (lane < 16) {
      float inv = 1.f / fmaxf((float)deg, 1.f);
      float4 r;
      r.x = acc.x * inv; r.y = acc.y * inv; r.z = acc.z * inv; r.w = acc.w * inv;
      reinterpret_cast<float4*>(&agg[(size_t)wid * 64])[cl] = r;
    }
  } else {
    float acc = 0.f;
    for (int e = beg; e < end; ++e) acc += h3[(size_t)csr_src[e] * 64 + lane];
    agg[(size_t)wid * 64 + lane] = acc / fmaxf((float)deg, 1.f);
  }
}

// ---------------------------------------------------------------- SAGE GEMM
__global__ __launch_bounds__(256) void k_sage_mm(
    const float* __restrict__ agg, const float* __restrict__ h3,
    const float* __restrict__ Wl, const float* __restrict__ Wr,
    const float* __restrict__ bias, float* __restrict__ out) {
  __shared__ float WlS[4096];
  __shared__ float WrS[4096];
  __shared__ float Ag[2048];
  __shared__ float Hr[2048];
  int t = threadIdx.x;
  for (int i = t; i < 4096; i += 256) { WlS[i] = Wl[i]; WrS[i] = Wr[i]; }
  int ct = t & 15, rg = t >> 4;
  float4 bv = reinterpret_cast<const float4*>(bias)[ct];
  for (int r0 = blockIdx.x * 32; r0 < NN; r0 += gridDim.x * 32) {
    for (int i = t; i < 2048; i += 256) {
      int n = r0 + (i >> 6);
      float va = 0.f, vh = 0.f;
      if (n < NN) {
        va = agg[(size_t)n * 64 + (i & 63)];
        vh = h3[(size_t)n * 64 + (i & 63)];
      }
      Ag[i] = va; Hr[i] = vh;
    }
    __syncthreads();
    float4 c0 = {0.f, 0.f, 0.f, 0.f}, c1 = c0;
    const float* a0 = &Ag[(rg * 2 + 0) * 64];
    const float* a1 = &Ag[(rg * 2 + 1) * 64];
    const float* h0 = &Hr[(rg * 2 + 0) * 64];
    const float* h1 = &Hr[(rg * 2 + 1) * 64];
    #pragma unroll 4
    for (int k = 0; k < 64; k += 4) {
      float4 wl0 = *reinterpret_cast<const float4*>(&WlS[(k + 0) * 64 + ct * 4]);
      float4 wl1 = *reinterpret_cast<const float4*>(&WlS[(k + 1) * 64 + ct * 4]);
      float4 wl2 = *reinterpret_cast<const float4*>(&WlS[(k + 2) * 64 + ct * 4]);
      float4 wl3 = *reinterpret_cast<const float4*>(&WlS[(k + 3) * 64 + ct * 4]);
      float4 wr0 = *reinterpret_cast<const float4*>(&WrS[(k + 0) * 64 + ct * 4]);
      float4 wr1 = *reinterpret_cast<const float4*>(&WrS[(k + 1) * 64 + ct * 4]);
      float4 wr2 = *reinterpret_cast<const float4*>(&WrS[(k + 2) * 64 + ct * 4]);
      float4 wr3 = *reinterpret_cast<const float4*>(&WrS[(k + 3) * 64 + ct * 4]);
      float4 aa0 = *reinterpret_cast<const float4*>(&a0[k]);
      float4 aa1 = *reinterpret_cast<const float4*>(&a1[k]);
      float4 hh0 = *reinterpret_cast<const float4*>(&h0[k]);
      float4 hh1 = *reinterpret_cast<const float4*>(&h1[k]);
      c0 = f4fma(aa0.x, wl0, c0); c0 = f4fma(aa0.y, wl1, c0);
      c0 = f4fma(aa0.z, wl2, c0); c0 = f4fma(aa0.w, wl3, c0);
      c0 = f4fma(hh0.x, wr0, c0); c0 = f4fma(hh0.y, wr1, c0);
      c0 = f4fma(hh0.z, wr2, c0); c0 = f4fma(hh0.w, wr3, c0);
      c1 = f4fma(aa1.x, wl0, c1); c1 = f4fma(aa1.y, wl1, c1);
      c1 = f4fma(aa1.z, wl2, c1); c1 = f4fma(aa1.w, wl3, c1);
      c1 = f4fma(hh1.x, wr0, c1); c1 = f4fma(hh1.y, wr1, c1);
      c1 = f4fma(hh1.z, wr2, c1); c1 = f4fma(hh1.w, wr3, c1);
    }
    int n0 = r0 + rg * 2;
    if (n0 + 0 < NN) {
      float4 r;
      r.x = eluf(c0.x + bv.x); r.y = eluf(c0.y + bv.y);
      r.z = eluf(c0.z + bv.z); r.w = eluf(c0.w + bv.w);
      *reinterpret_cast<float4*>(&out[(size_t)(n0 + 0) * 64 + ct * 4]) = r;
    }
    if (n0 + 1 < NN) {
      float4 r;
      r.x = eluf(c1.x + bv.x); r.y = eluf(c1.y + bv.y);
      r.z = eluf(c1.z + bv.z); r.w = eluf(c1.w + bv.w);
      *reinterpret_cast<float4*>(&out[(size_t)(n0 + 1) * 64 + ct * 4]) = r;
    }
    __syncthreads();
  }
}

// ---------------------------------------------------------------- pooling
__global__ __launch_bounds__(256) void k_pool2(const float* __restrict__ hs,
                                               const int* __restrict__ batch,
                                               float* __restrict__ g) {
  int cid = (blockIdx.x << 2) + (threadIdx.x >> 6);
  int lane = threadIdx.x & 63;
  int n0 = cid * 32;
  if (n0 >= NN) return;
  int n1 = n0 + 32 < NN ? n0 + 32 : NN;
  int cur = batch[n0];
  float acc = 0.f;
  for (int n = n0; n < n1; ++n) {
    int b = batch[n];
    if (b != cur) {
      atomicAdd(&g[cur * 64 + lane], acc);
      acc = 0.f;
      cur = b;
    }
    acc += hs[(size_t)n * 64 + lane];
  }
  atomicAdd(&g[cur * 64 + lane], acc);
}

// ---------------------------------------------------------------- MLP head
__device__ __forceinline__ int lowerb(const int* __restrict__ a, int n, int key) {
  int lo = 0, hi = n;
  while (lo < hi) { int mid = (lo + hi) >> 1; if (a[mid] < key) lo = mid + 1; else hi = mid; }
  return lo;
}

__global__ __launch_bounds__(256) void k_head(
    const float* __restrict__ g, const int* __restrict__ batch,
    const float* __restrict__ l1W, const float* __restrict__ l1b,
    const float* __restrict__ l2W, const float* __restrict__ l2b,
    const float* __restrict__ telW, const float* __restrict__ telb,
    const float* __restrict__ compW, const float* __restrict__ compb,
    const float* __restrict__ pchW, const float* __restrict__ pchb,
    float* __restrict__ out) {
  __shared__ float gS[4096];
  __shared__ float WS[4096];
  __shared__ float hS[4096];
  __shared__ float invc[64];
  int t = threadIdx.x;
  if (t < 64) {
    int lo = lowerb(batch, NN, t), hi = lowerb(batch, NN, t + 1);
    invc[t] = 1.f / fmaxf((float)(hi - lo), 1.f);
  }
  for (int i = t; i < 4096; i += 256) WS[i] = l1W[i];
  __syncthreads();
  for (int i = t; i < 4096; i += 256) gS[i] = g[i] * invc[i >> 6];
  __syncthreads();
  for (int i = t; i < 4096; i += 256) {
    int r = i >> 6, j = i & 63;
    float s = 0.f;
    for (int k = 0; k < 64; ++k) s += gS[r * 64 + k] * WS[k * 64 + j];
    hS[i] = eluf(s + l1b[j]);
  }
  __syncthreads();
  for (int i = t; i < 4096; i += 256) WS[i] = l2W[i];
  __syncthreads();
  for (int i = t; i < 4096; i += 256) {
    int r = i >> 6, j = i & 63;
    float s = 0.f;
    for (int k = 0; k < 64; ++k) s += hS[r * 64 + k] * WS[k * 64 + j];
    gS[i] = s + l2b[j];
  }
  __syncthreads();
  if (t < 192) {
    int head = t >> 6, r = t & 63;
    const float* Wv = head == 0 ? telW : (head == 1 ? compW : pchW);
    float bb = head == 0 ? telb[0] : (head == 1 ? compb[0] : pchb[0]);
    float s = 0.f;
    for (int k = 0; k < 64; ++k) s += gS[r * 64 + k] * Wv[k];
    out[t] = s + bb;
  }
}

// ---------------------------------------------------------------- launch
extern "C" void kernel_launch(void* const* d_in, const int* in_sizes, int n_in,
                              void* d_out, int out_size, void* d_ws, size_t ws_size,
                              hipStream_t stream) {
  const float* x     = (const float*)d_in[0];
  const int*   eidx  = (const int*)d_in[1];
  const float* eattr = (const float*)d_in[2];
  const int*   batch = (const int*)d_in[3];
  const int*   ntype = (const int*)d_in[4];
  const float* nemb  = (const float*)d_in[5];
  const float* edgeW = (const float*)d_in[6];
  const float* edgeB = (const float*)d_in[7];
  const float* W1    = (const float*)d_in[8];
  const float* atts1 = (const float*)d_in[9];
  const float* attd1 = (const float*)d_in[10];
  const float* We1   = (const float*)d_in[11];
  const float* atte1 = (const float*)d_in[12];
  const float* b1    = (const float*)d_in[13];
  const float* W2    = (const float*)d_in[14];
  const float* atts2 = (const float*)d_in[15];
  const float* attd2 = (const float*)d_in[16];
  const float* We2   = (const float*)d_in[17];
  const float* atte2 = (const float*)d_in[18];
  const float* b2    = (const float*)d_in[19];
  const float* sageWl = (const float*)d_in[20];
  const float* sageWr = (const float*)d_in[21];
  const float* sageB  = (const float*)d_in[22];
  const float* l1W = (const float*)d_in[23];
  const float* l1b = (const float*)d_in[24];
  const float* l2W = (const float*)d_in[25];
  const float* l2b = (const float*)d_in[26];
  const float* telW  = (const float*)d_in[27];
  const float* telb  = (const float*)d_in[28];
  const float* compW = (const float*)d_in[29];
  const float* compb = (const float*)d_in[30];
  const float* pchW  = (const float*)d_in[31];
  const float* pchb  = (const float*)d_in[32];

  char* wp = (char*)d_ws;
  auto alloc = [&](size_t bytes) -> char* {
    char* p = wp;
    wp += (bytes + 255) & ~(size_t)255;
    return p;
  };
  float*  pq      = (float*)alloc(16 * 4);
  int*    cnt     = (int*)alloc((size_t)NN * 4);
  int*    off     = (int*)alloc(((size_t)NN + 1) * 4);
  int*    csr_src = (int*)alloc((size_t)NE * 4);
  float*  csr_ea  = (float*)alloc((size_t)NE * 4);
  float*  as_     = (float*)alloc((size_t)NN * 16);
  float*  ad_     = (float*)alloc((size_t)NN * 16);
  bf16*   hmat    = (bf16*)alloc((size_t)NN * 256 * 2);
  float*  nodeB   = (float*)alloc((size_t)NN * 64 * 4);
  float*  aggbuf  = (float*)alloc((size_t)NN * 64 * 4);
  unsigned short* B1h = (unsigned short*)alloc(256 * 96 * 2);
  unsigned short* B1l = (unsigned short*)alloc(256 * 96 * 2);
  unsigned short* B2h = (unsigned short*)alloc(256 * 64 * 2);
  unsigned short* B2l = (unsigned short*)alloc(256 * 64 * 2);
  // overlaid region R: A1 planes (19.2MB) -> A2 planes (12.8MB) -> sage out
  char* R = alloc((size_t)NN * 96 * 2 * 2);
  unsigned short* A1h = (unsigned short*)R;
  unsigned short* A1l = A1h + (size_t)NN * 96;
  unsigned short* A2h = (unsigned short*)R;
  unsigned short* A2l = A2h + (size_t)NN * 64;
  float* sageout = (float*)R;
  float* gbuf = (float*)alloc(64 * 64 * 4);

  const int* srcI = eidx;
  const int* dstI = eidx + NE;

  hipMemsetAsync(cnt, 0, (size_t)NN * 4, stream);
  hipMemsetAsync(gbuf, 0, 64 * 64 * 4, stream);
  k_prep<<<97, 256, 0, stream>>>(W1, W2, We1, atte1, We2, atte2, edgeW, edgeB,
                                 B1h, B1l, B2h, B2l, pq);
  k_hist<<<(NE + 255) / 256, 256, 0, stream>>>(dstI, cnt);
  k_scan<<<1, 1024, 0, stream>>>(cnt, off);
  k_scatter<<<(NE + 255) / 256, 256, 0, stream>>>(srcI, dstI, eattr, off, cnt,
                                                  csr_src, csr_ea);
  k_splitA<<<2048, 256, 0, stream>>>(x, ntype, nemb, A1h, A1l);
  // GAT layer 1
  k_mm_mfma<96><<<(NN + 63) / 64, 256, 0, stream>>>(
      A1h, A1l, B1h, B1l, atts1, attd1, hmat, as_, ad_);
  k_gat<<<NN / 4, 256, 0, stream>>>(off, csr_src, csr_ea, as_, ad_, pq, 0,
                                    hmat, b1, nullptr, A2h, A2l);
  // GAT layer 2
  k_mm_mfma<64><<<(NN + 63) / 64, 256, 0, stream>>>(
      A2h, A2l, B2h, B2l, atts2, attd2, hmat, as_, ad_);
  k_gat<<<NN / 4, 256, 0, stream>>>(off, csr_src, csr_ea, as_, ad_, pq, 8,
                                    hmat, b2, nodeB, nullptr, nullptr);
  // SAGE + pool + head
  k_agg<<<NN / 4, 256, 0, stream>>>(off, csr_src, nodeB, aggbuf);
  k_sage_mm<<<1024, 256, 0, stream>>>(aggbuf, nodeB, sageWl, sageWr, sageB,
                                      sageout);
  k_pool2<<<((NN + 31) / 32 + 3) / 4, 256, 0, stream>>>(sageout, batch, gbuf);
  k_head<<<1, 256, 0, stream>>>(gbuf, batch, l1W, l1b, l2W, l2b, telW, telb,
                                compW, compb, pchW, pchb, (float*)d_out);
}

// Round 10
// 452.243 us; speedup vs baseline: 1.1809x; 1.1809x over previous
//
#include <hip/hip_runtime.h>
#include <hip/hip_bf16.h>

// EnhancedTelomeraseGNN on MI355X — round 10.
// f32 in/out. GEMMs on MFMA (16x16x32 bf16, split-bf16 hi/lo). a_e=ea*p+q.
// Round-10: REVERT round-9's k_scan (single-block strided walk, 79us) and
// k_gat/k_agg channel-split (bpermute in the address chain, -BW +VALU) back
// to the round-8 structures. Keep: k_prep fold, atomicSub scatter.
// New: pass-B gather unroll 4->8 in k_gat and k_agg (doubles rows in flight;
// deg~Poisson(8) so the 8-batch covers most edges).
//
// Workspace (~76 MB, overlaid): pq | cnt | off | csr_src | csr_ea | as | ad |
// hmat bf16[N,256] | nodeB f32[N,64] | agg f32[N,64] | B-planes | R(19.2MB):
// A1 planes -> A2 planes -> sage-out f32 | gbuf.

#define NN 50000
#define NE 400000
#define FIN 32
#define NBATCH 64

typedef __hip_bfloat16 bf16;
typedef short bf16x8 __attribute__((ext_vector_type(8)));
typedef float f32x4 __attribute__((ext_vector_type(4)));

__device__ __forceinline__ float b2f(bf16 v) { return __bfloat162float(v); }
__device__ __forceinline__ float lrelu(float x) { return x > 0.f ? x : 0.2f * x; }
__device__ __forceinline__ float eluf(float x) { return x > 0.f ? x : (expf(x) - 1.f); }

__device__ __forceinline__ float4 f4fma(float s, float4 w, float4 c) {
  c.x = fmaf(s, w.x, c.x); c.y = fmaf(s, w.y, c.y);
  c.z = fmaf(s, w.z, c.z); c.w = fmaf(s, w.w, c.w);
  return c;
}

__device__ __forceinline__ float4 upk4(uint2 u) {
  float4 f;
  f.x = __uint_as_float(u.x << 16);
  f.y = __uint_as_float(u.x & 0xffff0000u);
  f.z = __uint_as_float(u.y << 16);
  f.w = __uint_as_float(u.y & 0xffff0000u);
  return f;
}

__device__ __forceinline__ unsigned short bfbits(float f) {
  bf16 b = __float2bfloat16(f);
  unsigned short u;
  __builtin_memcpy(&u, &b, 2);
  return u;
}
__device__ __forceinline__ float hi_f(unsigned short u) {
  return __uint_as_float((unsigned int)u << 16);
}

// ------------------------------------------------------- prep: splitW + pq
__global__ __launch_bounds__(256) void k_prep(
    const float* __restrict__ W1, const float* __restrict__ W2,
    const float* __restrict__ We1, const float* __restrict__ atte1,
    const float* __restrict__ We2, const float* __restrict__ atte2,
    const float* __restrict__ edgeW, const float* __restrict__ edgeB,
    unsigned short* __restrict__ B1h, unsigned short* __restrict__ B1l,
    unsigned short* __restrict__ B2h, unsigned short* __restrict__ B2l,
    float* __restrict__ pq) {
  if (blockIdx.x == 96) {
    int t = threadIdx.x, h = t >> 6, c = t & 63;
    float sW1 = 0.f, sB1 = 0.f, sW2 = 0.f, sB2 = 0.f;
    for (int j = 0; j < 64; ++j) {
      float w = edgeW[j], b = edgeB[j];
      float we1 = We1[j * 256 + h * 64 + c];
      float we2 = We2[j * 256 + h * 64 + c];
      sW1 += w * we1; sB1 += b * we1;
      sW2 += w * we2; sB2 += b * we2;
    }
    float a1 = atte1[h * 64 + c], a2 = atte2[h * 64 + c];
    float p1 = sW1 * a1, q1 = sB1 * a1, p2 = sW2 * a2, q2 = sB2 * a2;
    for (int o = 32; o; o >>= 1) {
      p1 += __shfl_xor(p1, o); q1 += __shfl_xor(q1, o);
      p2 += __shfl_xor(p2, o); q2 += __shfl_xor(q2, o);
    }
    if (c == 0) { pq[h] = p1; pq[4 + h] = q1; pq[8 + h] = p2; pq[12 + h] = q2; }
    return;
  }
  int t = blockIdx.x * 256 + threadIdx.x;
  if (t < 256 * 96) {
    int n = t / 96, k = t - n * 96;
    float v = W1[k * 256 + n];
    unsigned short h = bfbits(v);
    B1h[t] = h; B1l[t] = bfbits(v - hi_f(h));
  }
  if (t < 256 * 64) {
    int n = t >> 6, k = t & 63;
    float v = W2[k * 256 + n];
    unsigned short h = bfbits(v);
    B2h[t] = h; B2l[t] = bfbits(v - hi_f(h));
  }
}

// ---------------------------------------------------------------- CSR build
__global__ void k_hist(const int* __restrict__ dst, int* __restrict__ cnt) {
  int e = blockIdx.x * 256 + threadIdx.x;
  if (e < NE) atomicAdd(&cnt[dst[e]], 1);
}

// round-8 scan: coalesced 1024-wide tiles, barriered carry (reads cnt only).
__global__ __launch_bounds__(1024) void k_scan(const int* __restrict__ cnt,
                                               int* __restrict__ off) {
  __shared__ int wsum[16];
  __shared__ int carry;
  int t = threadIdx.x, lane = t & 63, w = t >> 6;
  if (t == 0) { carry = 0; off[0] = 0; }
  __syncthreads();
  for (int base = 0; base < NN; base += 1024) {
    int idx = base + t;
    int v = (idx < NN) ? cnt[idx] : 0;
    int s = v;
    for (int o = 1; o < 64; o <<= 1) { int u = __shfl_up(s, o); if (lane >= o) s += u; }
    if (lane == 63) wsum[w] = s;
    __syncthreads();
    if (t < 16) {
      int ws = wsum[t];
      for (int o = 1; o < 16; o <<= 1) { int u = __shfl_up(ws, o); if (t >= o) ws += u; }
      wsum[t] = ws;
    }
    __syncthreads();
    int add = carry + (w ? wsum[w - 1] : 0);
    if (idx < NN) off[idx + 1] = add + s;
    __syncthreads();
    if (t == 0) carry += wsum[15];
    __syncthreads();
  }
}

// scatter via atomicSub on live cnt (slot = off[d] + remaining - 1)
__global__ void k_scatter(const int* __restrict__ src, const int* __restrict__ dst,
                          const float* __restrict__ ea, const int* __restrict__ off,
                          int* __restrict__ cnt, int* __restrict__ csr_src,
                          float* __restrict__ csr_ea) {
  int e = blockIdx.x * 256 + threadIdx.x;
  if (e >= NE) return;
  int d = dst[e];
  int r = atomicSub(&cnt[d], 1);
  int slot = off[d] + r - 1;
  csr_src[slot] = src[e];
  csr_ea[slot] = ea[e];
}

// ---------------------------------------------------------------- split prep
__global__ __launch_bounds__(256) void k_splitA(
    const float* __restrict__ x, const int* __restrict__ ntype,
    const float* __restrict__ emb, unsigned short* __restrict__ Ah,
    unsigned short* __restrict__ Al) {
  const int total = NN * 96;
  for (int i = blockIdx.x * 256 + threadIdx.x; i < total; i += gridDim.x * 256) {
    int n = i / 96, k = i - n * 96;
    float v = (k < FIN) ? x[n * FIN + k] : emb[ntype[n] * 64 + (k - FIN)];
    unsigned short h = bfbits(v);
    Ah[i] = h;
    Al[i] = bfbits(v - hi_f(h));
  }
}

// ---------------------------------------------------------------- MFMA GEMM
template <int K>
__global__ __launch_bounds__(256) void k_mm_mfma(
    const unsigned short* __restrict__ Ah, const unsigned short* __restrict__ Al,
    const unsigned short* __restrict__ Bh, const unsigned short* __restrict__ Bl,
    const float* __restrict__ atts, const float* __restrict__ attd,
    bf16* __restrict__ hmat, float* __restrict__ as_, float* __restrict__ ad_) {
  int m0 = blockIdx.x * 64;
  int w = threadIdx.x >> 6;     // wave = head
  int lane = threadIdx.x & 63;
  int lr = lane & 15;
  int lc = lane >> 4;
  float attsv[4], attdv[4];
  #pragma unroll
  for (int nt = 0; nt < 4; ++nt) {
    attsv[nt] = atts[w * 64 + nt * 16 + lr];
    attdv[nt] = attd[w * 64 + nt * 16 + lr];
  }
  f32x4 acc[4][4] = {};
  #pragma unroll
  for (int ks = 0; ks < K; ks += 32) {
    int koff = ks + lc * 8;
    bf16x8 ah[4], al[4], bh[4], bl[4];
    #pragma unroll
    for (int mt = 0; mt < 4; ++mt) {
      int m = m0 + mt * 16 + lr;
      if (m > NN - 1) m = NN - 1;
      ah[mt] = *reinterpret_cast<const bf16x8*>(&Ah[(size_t)m * K + koff]);
      al[mt] = *reinterpret_cast<const bf16x8*>(&Al[(size_t)m * K + koff]);
    }
    #pragma unroll
    for (int nt = 0; nt < 4; ++nt) {
      int n = w * 64 + nt * 16 + lr;
      bh[nt] = *reinterpret_cast<const bf16x8*>(&Bh[(size_t)n * K + koff]);
      bl[nt] = *reinterpret_cast<const bf16x8*>(&Bl[(size_t)n * K + koff]);
    }
    #pragma unroll
    for (int mt = 0; mt < 4; ++mt) {
      #pragma unroll
      for (int nt = 0; nt < 4; ++nt) {
        acc[mt][nt] = __builtin_amdgcn_mfma_f32_16x16x32_bf16(ah[mt], bh[nt], acc[mt][nt], 0, 0, 0);
        acc[mt][nt] = __builtin_amdgcn_mfma_f32_16x16x32_bf16(al[mt], bh[nt], acc[mt][nt], 0, 0, 0);
        acc[mt][nt] = __builtin_amdgcn_mfma_f32_16x16x32_bf16(ah[mt], bl[nt], acc[mt][nt], 0, 0, 0);
      }
    }
  }
  #pragma unroll
  for (int mt = 0; mt < 4; ++mt) {
    #pragma unroll
    for (int reg = 0; reg < 4; ++reg) {
      int row = m0 + mt * 16 + lc * 4 + reg;
      float sS = 0.f, sD = 0.f;
      #pragma unroll
      for (int nt = 0; nt < 4; ++nt) {
        float v = acc[mt][nt][reg];
        sS += v * attsv[nt];
        sD += v * attdv[nt];
      }
      for (int o = 1; o < 16; o <<= 1) {
        sS += __shfl_xor(sS, o);
        sD += __shfl_xor(sD, o);
      }
      if (row < NN) {
        #pragma unroll
        for (int nt = 0; nt < 4; ++nt)
          hmat[(size_t)row * 256 + w * 64 + nt * 16 + lr] =
              __float2bfloat16(acc[mt][nt][reg]);
        if (lr == 0) { as_[row * 4 + w] = sS; ad_[row * 4 + w] = sD; }
      }
    }
  }
}

// ---------------------------------------------------------------- GAT
// Round-8 structure; pass-B unrolled 8-deep (then 4, then tail).
__global__ __launch_bounds__(256) void k_gat(
    const int* __restrict__ off, const int* __restrict__ csr_src,
    const float* __restrict__ csr_ea, const float* __restrict__ as_,
    const float* __restrict__ ad_, const float* __restrict__ pq, int pqo,
    const bf16* __restrict__ hmat, const float* __restrict__ bias,
    float* __restrict__ outf, unsigned short* __restrict__ oph,
    unsigned short* __restrict__ opl) {
  __shared__ float wlds[4][256];
  int wv = threadIdx.x >> 6;
  int wid = (blockIdx.x << 2) + wv;
  int lane = threadIdx.x & 63;
  if (wid >= NN) return;
  int beg = off[wid], end = off[wid + 1];
  int deg = end - beg;
  int hsel = lane >> 4;
  float4 D = reinterpret_cast<const float4*>(ad_)[wid];
  float p0 = pq[pqo + 0], p1 = pq[pqo + 1], p2 = pq[pqo + 2], p3 = pq[pqo + 3];
  float q0 = pq[pqo + 4], q1 = pq[pqo + 5], q2 = pq[pqo + 6], q3 = pq[pqo + 7];
  float4 acc = {0.f, 0.f, 0.f, 0.f};

  if (deg <= 64) {
    bool valid = lane < deg;
    float lx = -INFINITY, ly = -INFINITY, lz = -INFINITY, lw = -INFINITY;
    if (valid) {
      int s = csr_src[beg + lane];
      float ea = csr_ea[beg + lane];
      float4 A = reinterpret_cast<const float4*>(as_)[s];
      lx = lrelu(A.x + D.x + ea * p0 + q0);
      ly = lrelu(A.y + D.y + ea * p1 + q1);
      lz = lrelu(A.z + D.z + ea * p2 + q2);
      lw = lrelu(A.w + D.w + ea * p3 + q3);
    }
    float m0 = lx, m1 = ly, m2 = lz, m3 = lw;
    for (int o = 32; o; o >>= 1) {
      m0 = fmaxf(m0, __shfl_xor(m0, o));
      m1 = fmaxf(m1, __shfl_xor(m1, o));
      m2 = fmaxf(m2, __shfl_xor(m2, o));
      m3 = fmaxf(m3, __shfl_xor(m3, o));
    }
    float w0 = valid ? __expf(lx - m0) : 0.f;
    float w1 = valid ? __expf(ly - m1) : 0.f;
    float w2 = valid ? __expf(lz - m2) : 0.f;
    float w3 = valid ? __expf(lw - m3) : 0.f;
    float s0 = w0, s1 = w1, s2 = w2, s3 = w3;
    for (int o = 32; o; o >>= 1) {
      s0 += __shfl_xor(s0, o); s1 += __shfl_xor(s1, o);
      s2 += __shfl_xor(s2, o); s3 += __shfl_xor(s3, o);
    }
    float4 wv4;
    wv4.x = w0 / (s0 + 1e-16f);
    wv4.y = w1 / (s1 + 1e-16f);
    wv4.z = w2 / (s2 + 1e-16f);
    wv4.w = w3 / (s3 + 1e-16f);
    reinterpret_cast<float4*>(&wlds[wv][0])[lane] = wv4;
    const float* wp = &wlds[wv][0];
    int j = 0;
    for (; j + 8 <= deg; j += 8) {
      int sA = csr_src[beg + j + 0];
      int sB = csr_src[beg + j + 1];
      int sC = csr_src[beg + j + 2];
      int sD = csr_src[beg + j + 3];
      int sE = csr_src[beg + j + 4];
      int sF = csr_src[beg + j + 5];
      int sG = csr_src[beg + j + 6];
      int sH = csr_src[beg + j + 7];
      float wA = wp[4 * (j + 0) + hsel];
      float wB = wp[4 * (j + 1) + hsel];
      float wC = wp[4 * (j + 2) + hsel];
      float wD = wp[4 * (j + 3) + hsel];
      float wE = wp[4 * (j + 4) + hsel];
      float wF = wp[4 * (j + 5) + hsel];
      float wG = wp[4 * (j + 6) + hsel];
      float wH = wp[4 * (j + 7) + hsel];
      uint2 uA = *reinterpret_cast<const uint2*>(&hmat[(size_t)sA * 256 + 4 * lane]);
      uint2 uB = *reinterpret_cast<const uint2*>(&hmat[(size_t)sB * 256 + 4 * lane]);
      uint2 uC = *reinterpret_cast<const uint2*>(&hmat[(size_t)sC * 256 + 4 * lane]);
      uint2 uD = *reinterpret_cast<const uint2*>(&hmat[(size_t)sD * 256 + 4 * lane]);
      uint2 uE = *reinterpret_cast<const uint2*>(&hmat[(size_t)sE * 256 + 4 * lane]);
      uint2 uF = *reinterpret_cast<const uint2*>(&hmat[(size_t)sF * 256 + 4 * lane]);
      uint2 uG = *reinterpret_cast<const uint2*>(&hmat[(size_t)sG * 256 + 4 * lane]);
      uint2 uH = *reinterpret_cast<const uint2*>(&hmat[(size_t)sH * 256 + 4 * lane]);
      acc = f4fma(wA, upk4(uA), acc);
      acc = f4fma(wB, upk4(uB), acc);
      acc = f4fma(wC, upk4(uC), acc);
      acc = f4fma(wD, upk4(uD), acc);
      acc = f4fma(wE, upk4(uE), acc);
      acc = f4fma(wF, upk4(uF), acc);
      acc = f4fma(wG, upk4(uG), acc);
      acc = f4fma(wH, upk4(uH), acc);
    }
    for (; j + 4 <= deg; j += 4) {
      int sA = csr_src[beg + j + 0];
      int sB = csr_src[beg + j + 1];
      int sC = csr_src[beg + j + 2];
      int sD = csr_src[beg + j + 3];
      float wA = wp[4 * (j + 0) + hsel];
      float wB = wp[4 * (j + 1) + hsel];
      float wC = wp[4 * (j + 2) + hsel];
      float wD = wp[4 * (j + 3) + hsel];
      uint2 uA = *reinterpret_cast<const uint2*>(&hmat[(size_t)sA * 256 + 4 * lane]);
      uint2 uB = *reinterpret_cast<const uint2*>(&hmat[(size_t)sB * 256 + 4 * lane]);
      uint2 uC = *reinterpret_cast<const uint2*>(&hmat[(size_t)sC * 256 + 4 * lane]);
      uint2 uD = *reinterpret_cast<const uint2*>(&hmat[(size_t)sD * 256 + 4 * lane]);
      acc = f4fma(wA, upk4(uA), acc);
      acc = f4fma(wB, upk4(uB), acc);
      acc = f4fma(wC, upk4(uC), acc);
      acc = f4fma(wD, upk4(uD), acc);
    }
    for (; j < deg; ++j) {
      int s = csr_src[beg + j];
      float w = wp[4 * j + hsel];
      uint2 u = *reinterpret_cast<const uint2*>(&hmat[(size_t)s * 256 + 4 * lane]);
      acc = f4fma(w, upk4(u), acc);
    }
  } else {
    // slow fallback for deg > 64
    float m0 = -INFINITY, m1 = -INFINITY, m2 = -INFINITY, m3 = -INFINITY;
    float s0 = 0.f, s1 = 0.f, s2 = 0.f, s3 = 0.f;
    for (int e = beg + lane; e < end; e += 64) {
      int s = csr_src[e];
      float ea = csr_ea[e];
      float4 A = reinterpret_cast<const float4*>(as_)[s];
      float lx = lrelu(A.x + D.x + ea * p0 + q0);
      float ly = lrelu(A.y + D.y + ea * p1 + q1);
      float lz = lrelu(A.z + D.z + ea * p2 + q2);
      float lw = lrelu(A.w + D.w + ea * p3 + q3);
      float nm;
      nm = fmaxf(m0, lx); s0 = s0 * __expf(m0 - nm) + __expf(lx - nm); m0 = nm;
      nm = fmaxf(m1, ly); s1 = s1 * __expf(m1 - nm) + __expf(ly - nm); m1 = nm;
      nm = fmaxf(m2, lz); s2 = s2 * __expf(m2 - nm) + __expf(lz - nm); m2 = nm;
      nm = fmaxf(m3, lw); s3 = s3 * __expf(m3 - nm) + __expf(lw - nm); m3 = nm;
    }
    for (int o = 32; o; o >>= 1) {
      float om, os, nm;
      om = __shfl_xor(m0, o); os = __shfl_xor(s0, o); nm = fmaxf(m0, om);
      s0 = s0 * __expf(fmaxf(m0 - nm, -80.f)) + os * __expf(fmaxf(om - nm, -80.f)); m0 = nm;
      om = __shfl_xor(m1, o); os = __shfl_xor(s1, o); nm = fmaxf(m1, om);
      s1 = s1 * __expf(fmaxf(m1 - nm, -80.f)) + os * __expf(fmaxf(om - nm, -80.f)); m1 = nm;
      om = __shfl_xor(m2, o); os = __shfl_xor(s2, o); nm = fmaxf(m2, om);
      s2 = s2 * __expf(fmaxf(m2 - nm, -80.f)) + os * __expf(fmaxf(om - nm, -80.f)); m2 = nm;
      om = __shfl_xor(m3, o); os = __shfl_xor(s3, o); nm = fmaxf(m3, om);
      s3 = s3 * __expf(fmaxf(m3 - nm, -80.f)) + os * __expf(fmaxf(om - nm, -80.f)); m3 = nm;
    }
    float i0 = 1.f / (s0 + 1e-16f), i1 = 1.f / (s1 + 1e-16f);
    float i2 = 1.f / (s2 + 1e-16f), i3 = 1.f / (s3 + 1e-16f);
    float Dh = hsel == 0 ? D.x : hsel == 1 ? D.y : hsel == 2 ? D.z : D.w;
    float ph = hsel == 0 ? p0 : hsel == 1 ? p1 : hsel == 2 ? p2 : p3;
    float qh = hsel == 0 ? q0 : hsel == 1 ? q1 : hsel == 2 ? q2 : q3;
    float mh = hsel == 0 ? m0 : hsel == 1 ? m1 : hsel == 2 ? m2 : m3;
    float ih = hsel == 0 ? i0 : hsel == 1 ? i1 : hsel == 2 ? i2 : i3;
    for (int j = beg; j < end; ++j) {
      int s = csr_src[j];
      float ea = csr_ea[j];
      float4 A = reinterpret_cast<const float4*>(as_)[s];
      float Ah = hsel == 0 ? A.x : hsel == 1 ? A.y : hsel == 2 ? A.z : A.w;
      float l = lrelu(Ah + Dh + ea * ph + qh);
      float w = __expf(l - mh) * ih;
      uint2 u = *reinterpret_cast<const uint2*>(&hmat[(size_t)s * 256 + 4 * lane]);
      acc = f4fma(w, upk4(u), acc);
    }
  }
  acc.x += __shfl_xor(acc.x, 16); acc.y += __shfl_xor(acc.y, 16);
  acc.z += __shfl_xor(acc.z, 16); acc.w += __shfl_xor(acc.w, 16);
  acc.x += __shfl_xor(acc.x, 32); acc.y += __shfl_xor(acc.y, 32);
  acc.z += __shfl_xor(acc.z, 32); acc.w += __shfl_xor(acc.w, 32);
  if (lane < 16) {
    float4 bv = reinterpret_cast<const float4*>(bias)[lane];
    float4 r;
    r.x = eluf(0.25f * acc.x + bv.x);
    r.y = eluf(0.25f * acc.y + bv.y);
    r.z = eluf(0.25f * acc.z + bv.z);
    r.w = eluf(0.25f * acc.w + bv.w);
    if (outf) reinterpret_cast<float4*>(&outf[(size_t)wid * 64])[lane] = r;
    if (oph) {
      ushort4 h4, l4;
      h4.x = bfbits(r.x); l4.x = bfbits(r.x - hi_f(h4.x));
      h4.y = bfbits(r.y); l4.y = bfbits(r.y - hi_f(h4.y));
      h4.z = bfbits(r.z); l4.z = bfbits(r.z - hi_f(h4.z));
      h4.w = bfbits(r.w); l4.w = bfbits(r.w - hi_f(h4.w));
      *reinterpret_cast<ushort4*>(&oph[(size_t)wid * 64 + lane * 4]) = h4;
      *reinterpret_cast<ushort4*>(&opl[(size_t)wid * 64 + lane * 4]) = l4;
    }
  }
}

// ---------------------------------------------------------------- SAGE agg
__global__ __launch_bounds__(256) void k_agg(
    const int* __restrict__ off, const int* __restrict__ csr_src,
    const float* __restrict__ h3, float* __restrict__ agg) {
  int wid = (blockIdx.x << 2) + (threadIdx.x >> 6);
  int lane = threadIdx.x & 63;
  if (wid >= NN) return;
  int beg = off[wid], end = off[wid + 1];
  float acc = 0.f;
  int e = beg;
  for (; e + 8 <= end; e += 8) {
    int s0 = csr_src[e + 0], s1 = csr_src[e + 1];
    int s2 = csr_src[e + 2], s3 = csr_src[e + 3];
    int s4 = csr_src[e + 4], s5 = csr_src[e + 5];
    int s6 = csr_src[e + 6], s7 = csr_src[e + 7];
    float v0 = h3[(size_t)s0 * 64 + lane];
    float v1 = h3[(size_t)s1 * 64 + lane];
    float v2 = h3[(size_t)s2 * 64 + lane];
    float v3 = h3[(size_t)s3 * 64 + lane];
    float v4 = h3[(size_t)s4 * 64 + lane];
    float v5 = h3[(size_t)s5 * 64 + lane];
    float v6 = h3[(size_t)s6 * 64 + lane];
    float v7 = h3[(size_t)s7 * 64 + lane];
    acc += ((v0 + v1) + (v2 + v3)) + ((v4 + v5) + (v6 + v7));
  }
  for (; e + 4 <= end; e += 4) {
    int s0 = csr_src[e + 0], s1 = csr_src[e + 1];
    int s2 = csr_src[e + 2], s3 = csr_src[e + 3];
    float v0 = h3[(size_t)s0 * 64 + lane];
    float v1 = h3[(size_t)s1 * 64 + lane];
    float v2 = h3[(size_t)s2 * 64 + lane];
    float v3 = h3[(size_t)s3 * 64 + lane];
    acc += (v0 + v1) + (v2 + v3);
  }
  for (; e < end; ++e) acc += h3[(size_t)csr_src[e] * 64 + lane];
  agg[(size_t)wid * 64 + lane] = acc / fmaxf((float)(end - beg), 1.f);
}

// ---------------------------------------------------------------- SAGE GEMM
__global__ __launch_bounds__(256) void k_sage_mm(
    const float* __restrict__ agg, const float* __restrict__ h3,
    const float* __restrict__ Wl, const float* __restrict__ Wr,
    const float* __restrict__ bias, float* __restrict__ out) {
  __shared__ float WlS[4096];
  __shared__ float WrS[4096];
  __shared__ float Ag[2048];
  __shared__ float Hr[2048];
  int t = threadIdx.x;
  for (int i = t; i < 4096; i += 256) { WlS[i] = Wl[i]; WrS[i] = Wr[i]; }
  int ct = t & 15, rg = t >> 4;
  float4 bv = reinterpret_cast<const float4*>(bias)[ct];
  for (int r0 = blockIdx.x * 32; r0 < NN; r0 += gridDim.x * 32) {
    for (int i = t; i < 2048; i += 256) {
      int n = r0 + (i >> 6);
      float va = 0.f, vh = 0.f;
      if (n < NN) {
        va = agg[(size_t)n * 64 + (i & 63)];
        vh = h3[(size_t)n * 64 + (i & 63)];
      }
      Ag[i] = va; Hr[i] = vh;
    }
    __syncthreads();
    float4 c0 = {0.f, 0.f, 0.f, 0.f}, c1 = c0;
    const float* a0 = &Ag[(rg * 2 + 0) * 64];
    const float* a1 = &Ag[(rg * 2 + 1) * 64];
    const float* h0 = &Hr[(rg * 2 + 0) * 64];
    const float* h1 = &Hr[(rg * 2 + 1) * 64];
    #pragma unroll 4
    for (int k = 0; k < 64; k += 4) {
      float4 wl0 = *reinterpret_cast<const float4*>(&WlS[(k + 0) * 64 + ct * 4]);
      float4 wl1 = *reinterpret_cast<const float4*>(&WlS[(k + 1) * 64 + ct * 4]);
      float4 wl2 = *reinterpret_cast<const float4*>(&WlS[(k + 2) * 64 + ct * 4]);
      float4 wl3 = *reinterpret_cast<const float4*>(&WlS[(k + 3) * 64 + ct * 4]);
      float4 wr0 = *reinterpret_cast<const float4*>(&WrS[(k + 0) * 64 + ct * 4]);
      float4 wr1 = *reinterpret_cast<const float4*>(&WrS[(k + 1) * 64 + ct * 4]);
      float4 wr2 = *reinterpret_cast<const float4*>(&WrS[(k + 2) * 64 + ct * 4]);
      float4 wr3 = *reinterpret_cast<const float4*>(&WrS[(k + 3) * 64 + ct * 4]);
      float4 aa0 = *reinterpret_cast<const float4*>(&a0[k]);
      float4 aa1 = *reinterpret_cast<const float4*>(&a1[k]);
      float4 hh0 = *reinterpret_cast<const float4*>(&h0[k]);
      float4 hh1 = *reinterpret_cast<const float4*>(&h1[k]);
      c0 = f4fma(aa0.x, wl0, c0); c0 = f4fma(aa0.y, wl1, c0);
      c0 = f4fma(aa0.z, wl2, c0); c0 = f4fma(aa0.w, wl3, c0);
      c0 = f4fma(hh0.x, wr0, c0); c0 = f4fma(hh0.y, wr1, c0);
      c0 = f4fma(hh0.z, wr2, c0); c0 = f4fma(hh0.w, wr3, c0);
      c1 = f4fma(aa1.x, wl0, c1); c1 = f4fma(aa1.y, wl1, c1);
      c1 = f4fma(aa1.z, wl2, c1); c1 = f4fma(aa1.w, wl3, c1);
      c1 = f4fma(hh1.x, wr0, c1); c1 = f4fma(hh1.y, wr1, c1);
      c1 = f4fma(hh1.z, wr2, c1); c1 = f4fma(hh1.w, wr3, c1);
    }
    int n0 = r0 + rg * 2;
    if (n0 + 0 < NN) {
      float4 r;
      r.x = eluf(c0.x + bv.x); r.y = eluf(c0.y + bv.y);
      r.z = eluf(c0.z + bv.z); r.w = eluf(c0.w + bv.w);
      *reinterpret_cast<float4*>(&out[(size_t)(n0 + 0) * 64 + ct * 4]) = r;
    }
    if (n0 + 1 < NN) {
      float4 r;
      r.x = eluf(c1.x + bv.x); r.y = eluf(c1.y + bv.y);
      r.z = eluf(c1.z + bv.z); r.w = eluf(c1.w + bv.w);
      *reinterpret_cast<float4*>(&out[(size_t)(n0 + 1) * 64 + ct * 4]) = r;
    }
    __syncthreads();
  }
}

// ---------------------------------------------------------------- pooling
__global__ __launch_bounds__(256) void k_pool2(const float* __restrict__ hs,
                                               const int* __restrict__ batch,
                                               float* __restrict__ g) {
  int cid = (blockIdx.x << 2) + (threadIdx.x >> 6);
  int lane = threadIdx.x & 63;
  int n0 = cid * 32;
  if (n0 >= NN) return;
  int n1 = n0 + 32 < NN ? n0 + 32 : NN;
  int cur = batch[n0];
  float acc = 0.f;
  for (int n = n0; n < n1; ++n) {
    int b = batch[n];
    if (b != cur) {
      atomicAdd(&g[cur * 64 + lane], acc);
      acc = 0.f;
      cur = b;
    }
    acc += hs[(size_t)n * 64 + lane];
  }
  atomicAdd(&g[cur * 64 + lane], acc);
}

// ---------------------------------------------------------------- MLP head
__device__ __forceinline__ int lowerb(const int* __restrict__ a, int n, int key) {
  int lo = 0, hi = n;
  while (lo < hi) { int mid = (lo + hi) >> 1; if (a[mid] < key) lo = mid + 1; else hi = mid; }
  return lo;
}

__global__ __launch_bounds__(256) void k_head(
    const float* __restrict__ g, const int* __restrict__ batch,
    const float* __restrict__ l1W, const float* __restrict__ l1b,
    const float* __restrict__ l2W, const float* __restrict__ l2b,
    const float* __restrict__ telW, const float* __restrict__ telb,
    const float* __restrict__ compW, const float* __restrict__ compb,
    const float* __restrict__ pchW, const float* __restrict__ pchb,
    float* __restrict__ out) {
  __shared__ float gS[4096];
  __shared__ float WS[4096];
  __shared__ float hS[4096];
  __shared__ float invc[64];
  int t = threadIdx.x;
  if (t < 64) {
    int lo = lowerb(batch, NN, t), hi = lowerb(batch, NN, t + 1);
    invc[t] = 1.f / fmaxf((float)(hi - lo), 1.f);
  }
  for (int i = t; i < 4096; i += 256) WS[i] = l1W[i];
  __syncthreads();
  for (int i = t; i < 4096; i += 256) gS[i] = g[i] * invc[i >> 6];
  __syncthreads();
  for (int i = t; i < 4096; i += 256) {
    int r = i >> 6, j = i & 63;
    float s = 0.f;
    for (int k = 0; k < 64; ++k) s += gS[r * 64 + k] * WS[k * 64 + j];
    hS[i] = eluf(s + l1b[j]);
  }
  __syncthreads();
  for (int i = t; i < 4096; i += 256) WS[i] = l2W[i];
  __syncthreads();
  for (int i = t; i < 4096; i += 256) {
    int r = i >> 6, j = i & 63;
    float s = 0.f;
    for (int k = 0; k < 64; ++k) s += hS[r * 64 + k] * WS[k * 64 + j];
    gS[i] = s + l2b[j];
  }
  __syncthreads();
  if (t < 192) {
    int head = t >> 6, r = t & 63;
    const float* Wv = head == 0 ? telW : (head == 1 ? compW : pchW);
    float bb = head == 0 ? telb[0] : (head == 1 ? compb[0] : pchb[0]);
    float s = 0.f;
    for (int k = 0; k < 64; ++k) s += gS[r * 64 + k] * Wv[k];
    out[t] = s + bb;
  }
}

// ---------------------------------------------------------------- launch
extern "C" void kernel_launch(void* const* d_in, const int* in_sizes, int n_in,
                              void* d_out, int out_size, void* d_ws, size_t ws_size,
                              hipStream_t stream) {
  const float* x     = (const float*)d_in[0];
  const int*   eidx  = (const int*)d_in[1];
  const float* eattr = (const float*)d_in[2];
  const int*   batch = (const int*)d_in[3];
  const int*   ntype = (const int*)d_in[4];
  const float* nemb  = (const float*)d_in[5];
  const float* edgeW = (const float*)d_in[6];
  const float* edgeB = (const float*)d_in[7];
  const float* W1    = (const float*)d_in[8];
  const float* atts1 = (const float*)d_in[9];
  const float* attd1 = (const float*)d_in[10];
  const float* We1   = (const float*)d_in[11];
  const float* atte1 = (const float*)d_in[12];
  const float* b1    = (const float*)d_in[13];
  const float* W2    = (const float*)d_in[14];
  const float* atts2 = (const float*)d_in[15];
  const float* attd2 = (const float*)d_in[16];
  const float* We2   = (const float*)d_in[17];
  const float* atte2 = (const float*)d_in[18];
  const float* b2    = (const float*)d_in[19];
  const float* sageWl = (const float*)d_in[20];
  const float* sageWr = (const float*)d_in[21];
  const float* sageB  = (const float*)d_in[22];
  const float* l1W = (const float*)d_in[23];
  const float* l1b = (const float*)d_in[24];
  const float* l2W = (const float*)d_in[25];
  const float* l2b = (const float*)d_in[26];
  const float* telW  = (const float*)d_in[27];
  const float* telb  = (const float*)d_in[28];
  const float* compW = (const float*)d_in[29];
  const float* compb = (const float*)d_in[30];
  const float* pchW  = (const float*)d_in[31];
  const float* pchb  = (const float*)d_in[32];

  char* wp = (char*)d_ws;
  auto alloc = [&](size_t bytes) -> char* {
    char* p = wp;
    wp += (bytes + 255) & ~(size_t)255;
    return p;
  };
  float*  pq      = (float*)alloc(16 * 4);
  int*    cnt     = (int*)alloc((size_t)NN * 4);
  int*    off     = (int*)alloc(((size_t)NN + 1) * 4);
  int*    csr_src = (int*)alloc((size_t)NE * 4);
  float*  csr_ea  = (float*)alloc((size_t)NE * 4);
  float*  as_     = (float*)alloc((size_t)NN * 16);
  float*  ad_     = (float*)alloc((size_t)NN * 16);
  bf16*   hmat    = (bf16*)alloc((size_t)NN * 256 * 2);
  float*  nodeB   = (float*)alloc((size_t)NN * 64 * 4);
  float*  aggbuf  = (float*)alloc((size_t)NN * 64 * 4);
  unsigned short* B1h = (unsigned short*)alloc(256 * 96 * 2);
  unsigned short* B1l = (unsigned short*)alloc(256 * 96 * 2);
  unsigned short* B2h = (unsigned short*)alloc(256 * 64 * 2);
  unsigned short* B2l = (unsigned short*)alloc(256 * 64 * 2);
  // overlaid region R: A1 planes (19.2MB) -> A2 planes (12.8MB) -> sage out
  char* R = alloc((size_t)NN * 96 * 2 * 2);
  unsigned short* A1h = (unsigned short*)R;
  unsigned short* A1l = A1h + (size_t)NN * 96;
  unsigned short* A2h = (unsigned short*)R;
  unsigned short* A2l = A2h + (size_t)NN * 64;
  float* sageout = (float*)R;
  float* gbuf = (float*)alloc(64 * 64 * 4);

  const int* srcI = eidx;
  const int* dstI = eidx + NE;

  hipMemsetAsync(cnt, 0, (size_t)NN * 4, stream);
  hipMemsetAsync(gbuf, 0, 64 * 64 * 4, stream);
  k_prep<<<97, 256, 0, stream>>>(W1, W2, We1, atte1, We2, atte2, edgeW, edgeB,
                                 B1h, B1l, B2h, B2l, pq);
  k_hist<<<(NE + 255) / 256, 256, 0, stream>>>(dstI, cnt);
  k_scan<<<1, 1024, 0, stream>>>(cnt, off);
  k_scatter<<<(NE + 255) / 256, 256, 0, stream>>>(srcI, dstI, eattr, off, cnt,
                                                  csr_src, csr_ea);
  k_splitA<<<2048, 256, 0, stream>>>(x, ntype, nemb, A1h, A1l);
  // GAT layer 1
  k_mm_mfma<96><<<(NN + 63) / 64, 256, 0, stream>>>(
      A1h, A1l, B1h, B1l, atts1, attd1, hmat, as_, ad_);
  k_gat<<<NN / 4, 256, 0, stream>>>(off, csr_src, csr_ea, as_, ad_, pq, 0,
                                    hmat, b1, nullptr, A2h, A2l);
  // GAT layer 2
  k_mm_mfma<64><<<(NN + 63) / 64, 256, 0, stream>>>(
      A2h, A2l, B2h, B2l, atts2, attd2, hmat, as_, ad_);
  k_gat<<<NN / 4, 256, 0, stream>>>(off, csr_src, csr_ea, as_, ad_, pq, 8,
                                    hmat, b2, nodeB, nullptr, nullptr);
  // SAGE + pool + head
  k_agg<<<NN / 4, 256, 0, stream>>>(off, csr_src, nodeB, aggbuf);
  k_sage_mm<<<1024, 256, 0, stream>>>(aggbuf, nodeB, sageWl, sageWr, sageB,
                                      sageout);
  k_pool2<<<((NN + 31) / 32 + 3) / 4, 256, 0, stream>>>(sageout, batch, gbuf);
  k_head<<<1, 256, 0, stream>>>(gbuf, batch, l1W, l1b, l2W, l2b, telW, telb,
                                compW, compb, pchW, pchb, (float*)d_out);
}